// Round 10
// baseline (236.787 us; speedup 1.0000x reference)
//
#include <hip/hip_runtime.h>

// ---------------------------------------------------------------------------
// 2-layer GCN:  out = Ahat * (relu(Ahat * X * W1 + b1)) * W2 + b2
// Ahat = D^-1/2 (A + I) D^-1/2, deg computed with self-loops.
//
// Round-10: wave-divergence cut in the aggregate. Waves process 4 nodes of
// near-equal degree via a per-bucket degree-sorted permutation (order[]),
// built inside k_bktcsr with an LDS counting sort. Gather traffic is
// unchanged (189 MB compulsory); only masked-lane iterations are removed.
// Scatter TPE 16->32 (runs of ~42 edges = 168B, half the reservations).
// ---------------------------------------------------------------------------

typedef __attribute__((ext_vector_type(8))) short bf16x8;
typedef __attribute__((ext_vector_type(4))) float f32x4;
typedef unsigned int uint;
typedef unsigned short ushort;

#define BKT_SHIFT 9
#define BKT_NODES 512   // nodes per bucket; NBK = ceil(N/512) <= 1024
#define TPE 32          // edges per thread in k_bktscatter

__device__ __forceinline__ ushort f2bf(float f) {  // RNE f32 -> bf16
  union { float f; uint u; } c; c.f = f;
  uint u = c.u;
  uint r = u + 0x7fffu + ((u >> 16) & 1u);
  return (ushort)(r >> 16);
}
__device__ __forceinline__ float bf_lo(uint u) {
  union { uint i; float f; } c; c.i = u << 16; return c.f;
}
__device__ __forceinline__ float bf_hi(uint u) {
  union { uint i; float f; } c; c.i = u & 0xffff0000u; return c.f;
}

// --------------------------- CSR build (single-pass, padded buckets) -------

// Scatter edges into padded bucket regions. Edges staged in registers
// (single global read); per-block LDS histogram -> one reservation atomic
// per (block,bucket) -> packed run writes. bcur holds RELATIVE counts
// (memset 0), absolute position = b*cap + rel.
__global__ __launch_bounds__(256) void k_bktscatter(const int* __restrict__ src,
                                                    const int* __restrict__ dst,
                                                    int* __restrict__ bcur,
                                                    uint* __restrict__ ebuf,
                                                    int E, int nbk, int cap) {
  __shared__ int h[1024];
  __shared__ int rbase[1024];
  int t = threadIdx.x;
  for (int i = t; i < nbk; i += 256) h[i] = 0;
  __syncthreads();
  int beg = blockIdx.x * (256 * TPE);
  int d[TPE], s[TPE];
#pragma unroll
  for (int j = 0; j < TPE; ++j) {
    int e = beg + j * 256 + t;
    bool v = e < E;
    d[j] = v ? dst[e] : -1;
    s[j] = v ? src[e] : 0;
    if (v) atomicAdd(&h[d[j] >> BKT_SHIFT], 1);
  }
  __syncthreads();
  for (int i = t; i < nbk; i += 256) {
    int c = h[i];
    rbase[i] = c ? atomicAdd(&bcur[i], c) : 0;  // relative base in bucket
    h[i] = 0;  // reuse as per-block cursor
  }
  __syncthreads();
#pragma unroll
  for (int j = 0; j < TPE; ++j) {
    if (d[j] >= 0) {
      int b = d[j] >> BKT_SHIFT;
      int rel = rbase[b] + atomicAdd(&h[b], 1);
      if (rel < cap)  // overflow guard (CAP ~ 1.5x mean)
        ebuf[(size_t)b * cap + rel] =
            ((uint)s[j] << BKT_SHIFT) | (uint)(d[j] & (BKT_NODES - 1));
    }
  }
}

// Exclusive scan of bucket counts (relative cursors) -> bbase.
__global__ __launch_bounds__(1024) void k_bktscan(const int* __restrict__ bcur,
                                                  int* __restrict__ bbase,
                                                  int nbk, int cap,
                                                  int* __restrict__ row_ptr, int N) {
  __shared__ int s[1024];
  int t = threadIdx.x;
  int c = 0;
  if (t < nbk) c = min(bcur[t], cap);
  s[t] = c;
  __syncthreads();
  for (int off = 1; off < 1024; off <<= 1) {
    int u = 0;
    if (t >= off) u = s[t - off];
    __syncthreads();
    if (t >= off) s[t] += u;
    __syncthreads();
  }
  if (t < nbk) bbase[t] = s[t] - c;            // exclusive
  if (t == nbk - 1) { bbase[nbk] = s[t]; row_ptr[N] = s[t]; }
}

// One block per bucket (512 nodes): LDS node-histogram -> scan -> row_ptr /
// dinv -> compact csr_src scatter -> LDS counting-sort of the bucket's nodes
// by degree -> order[] permutation (equal-degree nodes adjacent).
__global__ __launch_bounds__(256) void k_bktcsr(const uint* __restrict__ ebuf,
                                                const int* __restrict__ bbase,
                                                int cap,
                                                int* __restrict__ row_ptr,
                                                float* __restrict__ dinv,
                                                int* __restrict__ csr_src,
                                                int* __restrict__ order, int N) {
  __shared__ int ncnt[BKT_NODES];
  __shared__ int nscan[BKT_NODES];
  __shared__ int ncur[BKT_NODES];
  __shared__ int dhist[BKT_NODES];
  __shared__ int dbase[BKT_NODES];
  __shared__ int dcur[BKT_NODES];
  __shared__ int wtot[4];
  int t = threadIdx.x;
  int b = blockIdx.x;
  int node0 = b << BKT_SHIFT;
  int ebase = bbase[b];
  int cnt = bbase[b + 1] - ebase;
  const uint* ein = ebuf + (size_t)b * cap;
  ncnt[t] = 0; ncnt[t + 256] = 0;
  ncur[t] = 0; ncur[t + 256] = 0;
  dhist[t] = 0; dhist[t + 256] = 0;
  dcur[t] = 0; dcur[t + 256] = 0;
  __syncthreads();
  for (int e = t; e < cnt; e += 256)
    atomicAdd(&ncnt[ein[e] & (BKT_NODES - 1)], 1);
  __syncthreads();
  // exclusive scan of 512 counts: 2 elems/thread + wave scan + wave offsets
  int v0 = ncnt[2 * t], v1 = ncnt[2 * t + 1];
  int s = v0 + v1;
  int lane = t & 63, wv = t >> 6;
  int inc = s;
#pragma unroll
  for (int off = 1; off < 64; off <<= 1) {
    int u = __shfl_up(inc, off);
    if (lane >= off) inc += u;
  }
  if (lane == 63) wtot[wv] = inc;
  __syncthreads();
  int woff = 0;
  for (int i = 0; i < wv; ++i) woff += wtot[i];
  int ex = woff + inc - s;
  nscan[2 * t] = ex;
  nscan[2 * t + 1] = ex + v0;
  int n0 = node0 + 2 * t;
  if (n0 < N) {
    row_ptr[n0] = ebase + ex;
    dinv[n0] = rsqrtf((float)v0 + 1.0f);
  }
  if (n0 + 1 < N) {
    row_ptr[n0 + 1] = ebase + ex + v0;
    dinv[n0 + 1] = rsqrtf((float)v1 + 1.0f);
  }
  // degree histogram for the counting sort (valid nodes only)
  int d0 = min(v0, BKT_NODES - 1), d1 = min(v1, BKT_NODES - 1);
  if (n0 < N) atomicAdd(&dhist[d0], 1);
  if (n0 + 1 < N) atomicAdd(&dhist[d1], 1);
  __syncthreads();
  // csr_src scatter
  for (int e = t; e < cnt; e += 256) {
    uint u = ein[e];
    int l = u & (BKT_NODES - 1);
    int pos = ebase + nscan[l] + atomicAdd(&ncur[l], 1);
    csr_src[pos] = (int)(u >> BKT_SHIFT);
  }
  // exclusive scan of degree histogram -> dbase
  int w0 = dhist[2 * t], w1 = dhist[2 * t + 1];
  int ss = w0 + w1;
  int inc2 = ss;
#pragma unroll
  for (int off = 1; off < 64; off <<= 1) {
    int u = __shfl_up(inc2, off);
    if (lane >= off) inc2 += u;
  }
  __syncthreads();  // wtot reuse: prior reads complete
  if (lane == 63) wtot[wv] = inc2;
  __syncthreads();
  int woff2 = 0;
  for (int i = 0; i < wv; ++i) woff2 += wtot[i];
  int ex2 = woff2 + inc2 - ss;
  dbase[2 * t] = ex2;
  dbase[2 * t + 1] = ex2 + w0;
  __syncthreads();
  // emit degree-sorted node order (dense: valid nodes fill 0..valid-1)
  if (n0 < N) {
    int p = dbase[d0] + atomicAdd(&dcur[d0], 1);
    order[node0 + p] = n0;
  }
  if (n0 + 1 < N) {
    int p = dbase[d1] + atomicAdd(&dcur[d1], 1);
    order[node0 + p] = n0 + 1;
  }
}

// --------------------------- MFMA GEMM (dinv-scaled epilogue) --------------
// H'[n,128](bf16) = dinv[row] * (A[n,128] @ W[128,128]).
// A fp32 (layer1: X) or bf16 (layer2: h1). W staged in LDS chunk-major
// Bt[k/8][col][8]; frag layouts per m89.

__device__ __forceinline__ bf16x8 pack8(float4 u, float4 v) {
  bf16x8 r;
  r[0] = (short)f2bf(u.x); r[1] = (short)f2bf(u.y);
  r[2] = (short)f2bf(u.z); r[3] = (short)f2bf(u.w);
  r[4] = (short)f2bf(v.x); r[5] = (short)f2bf(v.y);
  r[6] = (short)f2bf(v.z); r[7] = (short)f2bf(v.w);
  return r;
}

template <bool A_IS_F32>
__global__ __launch_bounds__(256) void k_gemm_mfma(const void* __restrict__ A,
                                                   const float* __restrict__ Wf,
                                                   const float* __restrict__ dinv,
                                                   ushort* __restrict__ H, int n) {
  __shared__ __align__(16) ushort Bt[16 * 128 * 8];  // [chunk][col][8]
  int t = threadIdx.x;
  for (int id = t; id < 16 * 128; id += 256) {
    int col = id & 127, ch = id >> 7;
    ushort us[8];
#pragma unroll
    for (int j = 0; j < 8; ++j) us[j] = f2bf(Wf[(ch * 8 + j) * 128 + col]);
    uint4 p;
    p.x = (uint)us[0] | ((uint)us[1] << 16);
    p.y = (uint)us[2] | ((uint)us[3] << 16);
    p.z = (uint)us[4] | ((uint)us[5] << 16);
    p.w = (uint)us[6] | ((uint)us[7] << 16);
    *(uint4*)&Bt[id * 8] = p;
  }
  __syncthreads();

  int wv = t >> 6, lane = t & 63;
  int r16 = lane & 15, kg = lane >> 4;
  int row0 = blockIdx.x * 128 + wv * 32;
  f32x4 acc[2][8] = {};

#pragma unroll
  for (int ks = 0; ks < 4; ++ks) {
    bf16x8 a0, a1;
    if (A_IS_F32) {
      const float* Af = (const float*)A;
      int r = min(row0 + r16, n - 1);
      const float* p = &Af[(size_t)r * 128 + ks * 32 + kg * 8];
      a0 = pack8(*(const float4*)p, *(const float4*)(p + 4));
      r = min(row0 + 16 + r16, n - 1);
      p = &Af[(size_t)r * 128 + ks * 32 + kg * 8];
      a1 = pack8(*(const float4*)p, *(const float4*)(p + 4));
    } else {
      const ushort* Ab = (const ushort*)A;
      int r = min(row0 + r16, n - 1);
      a0 = *(const bf16x8*)&Ab[(size_t)r * 128 + ks * 32 + kg * 8];
      r = min(row0 + 16 + r16, n - 1);
      a1 = *(const bf16x8*)&Ab[(size_t)r * 128 + ks * 32 + kg * 8];
    }
#pragma unroll
    for (int tc = 0; tc < 8; ++tc) {
      bf16x8 b = *(const bf16x8*)&Bt[(((ks * 4 + kg) * 128) + tc * 16 + r16) * 8];
      acc[0][tc] = __builtin_amdgcn_mfma_f32_16x16x32_bf16(a0, b, acc[0][tc], 0, 0, 0);
      acc[1][tc] = __builtin_amdgcn_mfma_f32_16x16x32_bf16(a1, b, acc[1][tc], 0, 0, 0);
    }
  }

#pragma unroll
  for (int rt = 0; rt < 2; ++rt)
#pragma unroll
    for (int rg = 0; rg < 4; ++rg) {
      int row = row0 + rt * 16 + kg * 4 + rg;
      if (row < n) {
        float dv = dinv[row];
#pragma unroll
        for (int tc = 0; tc < 8; ++tc)
          H[(size_t)row * 128 + tc * 16 + r16] = f2bf(dv * acc[rt][tc][rg]);
      }
    }
}

// --------------------------- Aggregation -----------------------------------
// 4 nodes/wave via degree-sorted order[] (equal-degree nodes share a wave ->
// ~no masked iterations). sub=lane>>4 owns node, lane&15 covers 16B (8 cols).
// H pre-scaled by dinv[src]: inner loop = gather + 8 adds per edge.
// out_i = dinv_i * (h'_i + sum h'_src) + bias.  8-edge unroll for MLP.
// MODE 0: out bf16 + relu (layer 1).  MODE 1: out fp32 (layer 2).

__device__ __forceinline__ void add8(uint4 u, float* a) {
  a[0] += bf_lo(u.x); a[1] += bf_hi(u.x);
  a[2] += bf_lo(u.y); a[3] += bf_hi(u.y);
  a[4] += bf_lo(u.z); a[5] += bf_hi(u.z);
  a[6] += bf_lo(u.w); a[7] += bf_hi(u.w);
}

template <int MODE>
__global__ __launch_bounds__(256) void k_aggregate(
    const ushort* __restrict__ H, const int* __restrict__ csr_src,
    const int* __restrict__ row_ptr, const float* __restrict__ dinv,
    const int* __restrict__ order,
    const float* __restrict__ bias, ushort* __restrict__ outb,
    float* __restrict__ outf, int n) {
  int wave = (blockIdx.x * blockDim.x + threadIdx.x) >> 6;
  int lane = threadIdx.x & 63;
  int sub = lane >> 4, c16 = lane & 15;
  int idx = wave * 4 + sub;
  bool valid = idx < n;
  int nd = valid ? order[idx] : (n - 1);

  float di = dinv[nd];
  int beg = row_ptr[nd];
  int end = valid ? row_ptr[nd + 1] : beg;

  float acc[8] = {};
  uint4 sv = *(const uint4*)&H[(size_t)nd * 128 + c16 * 8];  // self (pre-scaled)
  add8(sv, acc);

  int e = beg;
  for (; e + 7 < end; e += 8) {
    int s[8];
    uint4 u[8];
#pragma unroll
    for (int j = 0; j < 8; ++j) s[j] = csr_src[e + j];
#pragma unroll
    for (int j = 0; j < 8; ++j)
      u[j] = *(const uint4*)&H[(size_t)s[j] * 128 + c16 * 8];
#pragma unroll
    for (int j = 0; j < 8; ++j) add8(u[j], acc);
  }
  for (; e + 3 < end; e += 4) {
    int s0 = csr_src[e], s1 = csr_src[e + 1];
    int s2 = csr_src[e + 2], s3 = csr_src[e + 3];
    uint4 u0 = *(const uint4*)&H[(size_t)s0 * 128 + c16 * 8];
    uint4 u1 = *(const uint4*)&H[(size_t)s1 * 128 + c16 * 8];
    uint4 u2 = *(const uint4*)&H[(size_t)s2 * 128 + c16 * 8];
    uint4 u3 = *(const uint4*)&H[(size_t)s3 * 128 + c16 * 8];
    add8(u0, acc); add8(u1, acc); add8(u2, acc); add8(u3, acc);
  }
  for (; e < end; ++e) {
    int s0 = csr_src[e];
    uint4 u0 = *(const uint4*)&H[(size_t)s0 * 128 + c16 * 8];
    add8(u0, acc);
  }

  float4 bA = *(const float4*)&bias[c16 * 8];
  float4 bB = *(const float4*)&bias[c16 * 8 + 4];
  float o[8];
  o[0] = fmaf(di, acc[0], bA.x); o[1] = fmaf(di, acc[1], bA.y);
  o[2] = fmaf(di, acc[2], bA.z); o[3] = fmaf(di, acc[3], bA.w);
  o[4] = fmaf(di, acc[4], bB.x); o[5] = fmaf(di, acc[5], bB.y);
  o[6] = fmaf(di, acc[6], bB.z); o[7] = fmaf(di, acc[7], bB.w);

  if (!valid) return;
  if (MODE == 0) {
#pragma unroll
    for (int i = 0; i < 8; ++i) o[i] = fmaxf(o[i], 0.f);
    uint4 w;
    w.x = (uint)f2bf(o[0]) | ((uint)f2bf(o[1]) << 16);
    w.y = (uint)f2bf(o[2]) | ((uint)f2bf(o[3]) << 16);
    w.z = (uint)f2bf(o[4]) | ((uint)f2bf(o[5]) << 16);
    w.w = (uint)f2bf(o[6]) | ((uint)f2bf(o[7]) << 16);
    *(uint4*)&outb[(size_t)nd * 128 + c16 * 8] = w;
  } else {
    *(float4*)&outf[(size_t)nd * 128 + c16 * 8] =
        make_float4(o[0], o[1], o[2], o[3]);
    *(float4*)&outf[(size_t)nd * 128 + c16 * 8 + 4] =
        make_float4(o[4], o[5], o[6], o[7]);
  }
}

// ---------------------------------------------------------------------------

extern "C" void kernel_launch(void* const* d_in, const int* in_sizes, int n_in,
                              void* d_out, int out_size, void* d_ws, size_t ws_size,
                              hipStream_t stream) {
  const float* x  = (const float*)d_in[0];
  const int* eidx = (const int*)d_in[1];
  const float* W1 = (const float*)d_in[2];
  const float* b1 = (const float*)d_in[3];
  const float* W2 = (const float*)d_in[4];
  const float* b2 = (const float*)d_in[5];
  float* out = (float*)d_out;

  const int N = in_sizes[0] / 128;
  const int E = in_sizes[1] / 2;
  const int* src = eidx;
  const int* dst = eidx + E;
  const int NBK = (N + BKT_NODES - 1) >> BKT_SHIFT;     // ~196 for N=100k
  const int CAP = (((E / NBK) * 3 / 2) + 255) & ~255;   // padded bucket cap

  auto align16 = [](size_t v) { return (v + 15) & ~(size_t)15; };
  char* w = (char*)d_ws;
  ushort* hb    = (ushort*)w; w += align16((size_t)N * 128 * 2);  // 25.6 MB
  ushort* h1b   = (ushort*)w; w += align16((size_t)N * 128 * 2);  // 25.6 MB
  int* csr_src  = (int*)w;    w += align16((size_t)E * 4);        // 6.4 MB
  int* row_ptr  = (int*)w;    w += align16((size_t)(N + 1) * 4);
  float* dinv   = (float*)w;  w += align16((size_t)N * 4);
  int* order    = (int*)w;    w += align16((size_t)N * 4);
  int* bbase    = (int*)w;    w += align16((size_t)(NBK + 1) * 4);
  int* bcur     = (int*)w;    w += align16((size_t)(NBK + 1) * 4);
  // padded edge buffer aliases h1b (NBK*CAP*4 ~ 9.6 MB < 25.6 MB); consumed
  // by k_bktcsr before aggregate-1 writes h1b (stream-ordered).
  uint* ebuf = (uint*)h1b;

  hipMemsetAsync(bcur, 0, (size_t)NBK * 4, stream);
  const int SCB = (E + 256 * TPE - 1) / (256 * TPE);  // scatter blocks (~196)
  k_bktscatter<<<SCB, 256, 0, stream>>>(src, dst, bcur, ebuf, E, NBK, CAP);
  k_bktscan<<<1, 1024, 0, stream>>>(bcur, bbase, NBK, CAP, row_ptr, N);
  k_bktcsr<<<NBK, 256, 0, stream>>>(ebuf, bbase, CAP, row_ptr, dinv, csr_src,
                                    order, N);

  const int GB = (N + 127) / 128;
  const int AGG_BLOCKS = ((N + 3) / 4 + 3) / 4;  // 4 nodes/wave, 4 waves/block
  // layer 1: hb = bf16(dinv * (X @ W1)); h1b = bf16(relu(dinv*sum + b1))
  k_gemm_mfma<true><<<GB, 256, 0, stream>>>(x, W1, dinv, hb, N);
  k_aggregate<0><<<AGG_BLOCKS, 256, 0, stream>>>(
      hb, csr_src, row_ptr, dinv, order, b1, h1b, nullptr, N);
  // layer 2: hb = bf16(dinv * (h1b @ W2)); out = dinv*sum + b2 (fp32)
  k_gemm_mfma<false><<<GB, 256, 0, stream>>>(h1b, W2, dinv, hb, N);
  k_aggregate<1><<<AGG_BLOCKS, 256, 0, stream>>>(
      hb, csr_src, row_ptr, dinv, order, b2, nullptr, out, N);
}

// Round 12
// 222.879 us; speedup vs baseline: 1.0624x; 1.0624x over previous
//
#include <hip/hip_runtime.h>

// ---------------------------------------------------------------------------
// 2-layer GCN:  out = Ahat * (relu(Ahat * X * W1 + b1)) * W2 + b2
// Ahat = D^-1/2 (A + I) D^-1/2, deg computed with self-loops.
//
// Round-12 = round-11 with the compile fix: __builtin_nontemporal_store
// requires clang ext_vector types, not HIP_vector_type (float4/uint4).
//  * round-9 sequential-node aggregate (degree-sort reverted in r11);
//  * aggregate output stores + csr_src loads NON-TEMPORAL (protect L2 for
//    the h-table gathers: h 25.6MB vs 4MB/XCD L2, hit ~55%);
//  * k_bktscan removed: csr_src in PADDED bucket layout, per-node (beg,deg)
//    in int2 rowinfo; bktcsr bucket-local only.
// ---------------------------------------------------------------------------

typedef __attribute__((ext_vector_type(8))) short bf16x8;
typedef __attribute__((ext_vector_type(4))) float f32x4;
typedef __attribute__((ext_vector_type(4))) unsigned int u32x4;
typedef unsigned int uint;
typedef unsigned short ushort;

#define BKT_SHIFT 9
#define BKT_NODES 512   // nodes per bucket; NBK = ceil(N/512) <= 1024
#define TPE 32          // edges per thread in k_bktscatter

__device__ __forceinline__ ushort f2bf(float f) {  // RNE f32 -> bf16
  union { float f; uint u; } c; c.f = f;
  uint u = c.u;
  uint r = u + 0x7fffu + ((u >> 16) & 1u);
  return (ushort)(r >> 16);
}
__device__ __forceinline__ float bf_lo(uint u) {
  union { uint i; float f; } c; c.i = u << 16; return c.f;
}
__device__ __forceinline__ float bf_hi(uint u) {
  union { uint i; float f; } c; c.i = u & 0xffff0000u; return c.f;
}

// --------------------------- CSR build (single-pass, padded buckets) -------

// Scatter edges into padded bucket regions. Edges staged in registers
// (single global read); per-block LDS histogram -> one reservation atomic
// per (block,bucket) -> packed run writes. bcur holds RELATIVE counts
// (memset 0), absolute position = b*cap + rel.
__global__ __launch_bounds__(256) void k_bktscatter(const int* __restrict__ src,
                                                    const int* __restrict__ dst,
                                                    int* __restrict__ bcur,
                                                    uint* __restrict__ ebuf,
                                                    int E, int nbk, int cap) {
  __shared__ int h[1024];
  __shared__ int rbase[1024];
  int t = threadIdx.x;
  for (int i = t; i < nbk; i += 256) h[i] = 0;
  __syncthreads();
  int beg = blockIdx.x * (256 * TPE);
  int d[TPE], s[TPE];
#pragma unroll
  for (int j = 0; j < TPE; ++j) {
    int e = beg + j * 256 + t;
    bool v = e < E;
    d[j] = v ? dst[e] : -1;
    s[j] = v ? src[e] : 0;
    if (v) atomicAdd(&h[d[j] >> BKT_SHIFT], 1);
  }
  __syncthreads();
  for (int i = t; i < nbk; i += 256) {
    int c = h[i];
    rbase[i] = c ? atomicAdd(&bcur[i], c) : 0;  // relative base in bucket
    h[i] = 0;  // reuse as per-block cursor
  }
  __syncthreads();
#pragma unroll
  for (int j = 0; j < TPE; ++j) {
    if (d[j] >= 0) {
      int b = d[j] >> BKT_SHIFT;
      int rel = rbase[b] + atomicAdd(&h[b], 1);
      if (rel < cap)  // overflow guard (CAP ~ 1.5x mean, ~+45 sigma)
        ebuf[(size_t)b * cap + rel] =
            ((uint)s[j] << BKT_SHIFT) | (uint)(d[j] & (BKT_NODES - 1));
    }
  }
}

// One block per bucket (512 nodes): LDS node-histogram -> local scan ->
// rowinfo(beg,deg)/dinv -> csr_src scatter into the bucket's PADDED region.
// No cross-bucket scan needed: beg = b*cap + local exclusive offset.
__global__ __launch_bounds__(256) void k_bktcsr(const uint* __restrict__ ebuf,
                                                const int* __restrict__ bcur,
                                                int cap,
                                                int2* __restrict__ rowinfo,
                                                float* __restrict__ dinv,
                                                int* __restrict__ csr_src, int N) {
  __shared__ int ncnt[BKT_NODES];
  __shared__ int nscan[BKT_NODES];
  __shared__ int ncur[BKT_NODES];
  __shared__ int wtot[4];
  int t = threadIdx.x;
  int b = blockIdx.x;
  int node0 = b << BKT_SHIFT;
  int ebase = b * cap;
  int cnt = min(bcur[b], cap);
  const uint* ein = ebuf + (size_t)ebase;
  ncnt[t] = 0; ncnt[t + 256] = 0;
  ncur[t] = 0; ncur[t + 256] = 0;
  __syncthreads();
  for (int e = t; e < cnt; e += 256)
    atomicAdd(&ncnt[ein[e] & (BKT_NODES - 1)], 1);
  __syncthreads();
  // exclusive scan of 512 counts: 2 elems/thread + wave scan + wave offsets
  int v0 = ncnt[2 * t], v1 = ncnt[2 * t + 1];
  int s = v0 + v1;
  int lane = t & 63, wv = t >> 6;
  int inc = s;
#pragma unroll
  for (int off = 1; off < 64; off <<= 1) {
    int u = __shfl_up(inc, off);
    if (lane >= off) inc += u;
  }
  if (lane == 63) wtot[wv] = inc;
  __syncthreads();
  int woff = 0;
  for (int i = 0; i < wv; ++i) woff += wtot[i];
  int ex = woff + inc - s;
  nscan[2 * t] = ex;
  nscan[2 * t + 1] = ex + v0;
  int n0 = node0 + 2 * t;
  if (n0 < N) {
    rowinfo[n0] = make_int2(ebase + ex, v0);
    dinv[n0] = rsqrtf((float)v0 + 1.0f);
  }
  if (n0 + 1 < N) {
    rowinfo[n0 + 1] = make_int2(ebase + ex + v0, v1);
    dinv[n0 + 1] = rsqrtf((float)v1 + 1.0f);
  }
  __syncthreads();
  for (int e = t; e < cnt; e += 256) {
    uint u = ein[e];
    int l = u & (BKT_NODES - 1);
    int pos = ebase + nscan[l] + atomicAdd(&ncur[l], 1);
    csr_src[pos] = (int)(u >> BKT_SHIFT);
  }
}

// --------------------------- MFMA GEMM (dinv-scaled epilogue) --------------
// H'[n,128](bf16) = dinv[row] * (A[n,128] @ W[128,128]).
// A fp32 (layer1: X) or bf16 (layer2: h1). W staged in LDS chunk-major
// Bt[k/8][col][8]; frag layouts per m89.

__device__ __forceinline__ bf16x8 pack8(float4 u, float4 v) {
  bf16x8 r;
  r[0] = (short)f2bf(u.x); r[1] = (short)f2bf(u.y);
  r[2] = (short)f2bf(u.z); r[3] = (short)f2bf(u.w);
  r[4] = (short)f2bf(v.x); r[5] = (short)f2bf(v.y);
  r[6] = (short)f2bf(v.z); r[7] = (short)f2bf(v.w);
  return r;
}

template <bool A_IS_F32>
__global__ __launch_bounds__(256) void k_gemm_mfma(const void* __restrict__ A,
                                                   const float* __restrict__ Wf,
                                                   const float* __restrict__ dinv,
                                                   ushort* __restrict__ H, int n) {
  __shared__ __align__(16) ushort Bt[16 * 128 * 8];  // [chunk][col][8]
  int t = threadIdx.x;
  for (int id = t; id < 16 * 128; id += 256) {
    int col = id & 127, ch = id >> 7;
    ushort us[8];
#pragma unroll
    for (int j = 0; j < 8; ++j) us[j] = f2bf(Wf[(ch * 8 + j) * 128 + col]);
    uint4 p;
    p.x = (uint)us[0] | ((uint)us[1] << 16);
    p.y = (uint)us[2] | ((uint)us[3] << 16);
    p.z = (uint)us[4] | ((uint)us[5] << 16);
    p.w = (uint)us[6] | ((uint)us[7] << 16);
    *(uint4*)&Bt[id * 8] = p;
  }
  __syncthreads();

  int wv = t >> 6, lane = t & 63;
  int r16 = lane & 15, kg = lane >> 4;
  int row0 = blockIdx.x * 128 + wv * 32;
  f32x4 acc[2][8] = {};

#pragma unroll
  for (int ks = 0; ks < 4; ++ks) {
    bf16x8 a0, a1;
    if (A_IS_F32) {
      const float* Af = (const float*)A;
      int r = min(row0 + r16, n - 1);
      const float* p = &Af[(size_t)r * 128 + ks * 32 + kg * 8];
      a0 = pack8(*(const float4*)p, *(const float4*)(p + 4));
      r = min(row0 + 16 + r16, n - 1);
      p = &Af[(size_t)r * 128 + ks * 32 + kg * 8];
      a1 = pack8(*(const float4*)p, *(const float4*)(p + 4));
    } else {
      const ushort* Ab = (const ushort*)A;
      int r = min(row0 + r16, n - 1);
      a0 = *(const bf16x8*)&Ab[(size_t)r * 128 + ks * 32 + kg * 8];
      r = min(row0 + 16 + r16, n - 1);
      a1 = *(const bf16x8*)&Ab[(size_t)r * 128 + ks * 32 + kg * 8];
    }
#pragma unroll
    for (int tc = 0; tc < 8; ++tc) {
      bf16x8 b = *(const bf16x8*)&Bt[(((ks * 4 + kg) * 128) + tc * 16 + r16) * 8];
      acc[0][tc] = __builtin_amdgcn_mfma_f32_16x16x32_bf16(a0, b, acc[0][tc], 0, 0, 0);
      acc[1][tc] = __builtin_amdgcn_mfma_f32_16x16x32_bf16(a1, b, acc[1][tc], 0, 0, 0);
    }
  }

#pragma unroll
  for (int rt = 0; rt < 2; ++rt)
#pragma unroll
    for (int rg = 0; rg < 4; ++rg) {
      int row = row0 + rt * 16 + kg * 4 + rg;
      if (row < n) {
        float dv = dinv[row];
#pragma unroll
        for (int tc = 0; tc < 8; ++tc)
          H[(size_t)row * 128 + tc * 16 + r16] = f2bf(dv * acc[rt][tc][rg]);
      }
    }
}

// --------------------------- Aggregation -----------------------------------
// 4 nodes/wave (sequential ids: protects csr_src streaming + write locality).
// sub=lane>>4 owns node, lane&15 covers 16B (8 bf16 cols) of the 256B row.
// H pre-scaled by dinv[src]: inner loop = gather + 8 adds per edge.
// out_i = dinv_i * (h'_i + sum h'_src) + bias.  8-edge unroll for MLP.
// Output stores + csr_src loads NON-TEMPORAL (protect L2 for h gathers).
// MODE 0: out bf16 + relu (layer 1).  MODE 1: out fp32 (layer 2).

__device__ __forceinline__ void add8(uint4 u, float* a) {
  a[0] += bf_lo(u.x); a[1] += bf_hi(u.x);
  a[2] += bf_lo(u.y); a[3] += bf_hi(u.y);
  a[4] += bf_lo(u.z); a[5] += bf_hi(u.z);
  a[6] += bf_lo(u.w); a[7] += bf_hi(u.w);
}

template <int MODE>
__global__ __launch_bounds__(256) void k_aggregate(
    const ushort* __restrict__ H, const int* __restrict__ csr_src,
    const int2* __restrict__ rowinfo, const float* __restrict__ dinv,
    const float* __restrict__ bias, ushort* __restrict__ outb,
    float* __restrict__ outf, int n) {
  int wave = (blockIdx.x * blockDim.x + threadIdx.x) >> 6;
  int lane = threadIdx.x & 63;
  int sub = lane >> 4, c16 = lane & 15;
  int node = wave * 4 + sub;
  bool valid = node < n;
  int nd = valid ? node : (n - 1);

  float di = dinv[nd];
  int2 ri = rowinfo[nd];
  int beg = ri.x;
  int end = beg + (valid ? ri.y : 0);

  float acc[8] = {};
  uint4 sv = *(const uint4*)&H[(size_t)nd * 128 + c16 * 8];  // self (pre-scaled)
  add8(sv, acc);

  int e = beg;
  for (; e + 7 < end; e += 8) {
    int s[8];
    uint4 u[8];
#pragma unroll
    for (int j = 0; j < 8; ++j) s[j] = __builtin_nontemporal_load(&csr_src[e + j]);
#pragma unroll
    for (int j = 0; j < 8; ++j)
      u[j] = *(const uint4*)&H[(size_t)s[j] * 128 + c16 * 8];
#pragma unroll
    for (int j = 0; j < 8; ++j) add8(u[j], acc);
  }
  for (; e + 3 < end; e += 4) {
    int s0 = __builtin_nontemporal_load(&csr_src[e]);
    int s1 = __builtin_nontemporal_load(&csr_src[e + 1]);
    int s2 = __builtin_nontemporal_load(&csr_src[e + 2]);
    int s3 = __builtin_nontemporal_load(&csr_src[e + 3]);
    uint4 u0 = *(const uint4*)&H[(size_t)s0 * 128 + c16 * 8];
    uint4 u1 = *(const uint4*)&H[(size_t)s1 * 128 + c16 * 8];
    uint4 u2 = *(const uint4*)&H[(size_t)s2 * 128 + c16 * 8];
    uint4 u3 = *(const uint4*)&H[(size_t)s3 * 128 + c16 * 8];
    add8(u0, acc); add8(u1, acc); add8(u2, acc); add8(u3, acc);
  }
  for (; e < end; ++e) {
    int s0 = __builtin_nontemporal_load(&csr_src[e]);
    uint4 u0 = *(const uint4*)&H[(size_t)s0 * 128 + c16 * 8];
    add8(u0, acc);
  }

  float4 bA = *(const float4*)&bias[c16 * 8];
  float4 bB = *(const float4*)&bias[c16 * 8 + 4];
  float o[8];
  o[0] = fmaf(di, acc[0], bA.x); o[1] = fmaf(di, acc[1], bA.y);
  o[2] = fmaf(di, acc[2], bA.z); o[3] = fmaf(di, acc[3], bA.w);
  o[4] = fmaf(di, acc[4], bB.x); o[5] = fmaf(di, acc[5], bB.y);
  o[6] = fmaf(di, acc[6], bB.z); o[7] = fmaf(di, acc[7], bB.w);

  if (!valid) return;
  if (MODE == 0) {
#pragma unroll
    for (int i = 0; i < 8; ++i) o[i] = fmaxf(o[i], 0.f);
    u32x4 w;
    w.x = (uint)f2bf(o[0]) | ((uint)f2bf(o[1]) << 16);
    w.y = (uint)f2bf(o[2]) | ((uint)f2bf(o[3]) << 16);
    w.z = (uint)f2bf(o[4]) | ((uint)f2bf(o[5]) << 16);
    w.w = (uint)f2bf(o[6]) | ((uint)f2bf(o[7]) << 16);
    __builtin_nontemporal_store(w, (u32x4*)&outb[(size_t)node * 128 + c16 * 8]);
  } else {
    f32x4 oa = {o[0], o[1], o[2], o[3]};
    f32x4 ob = {o[4], o[5], o[6], o[7]};
    __builtin_nontemporal_store(oa, (f32x4*)&outf[(size_t)node * 128 + c16 * 8]);
    __builtin_nontemporal_store(ob, (f32x4*)&outf[(size_t)node * 128 + c16 * 8 + 4]);
  }
}

// ---------------------------------------------------------------------------

extern "C" void kernel_launch(void* const* d_in, const int* in_sizes, int n_in,
                              void* d_out, int out_size, void* d_ws, size_t ws_size,
                              hipStream_t stream) {
  const float* x  = (const float*)d_in[0];
  const int* eidx = (const int*)d_in[1];
  const float* W1 = (const float*)d_in[2];
  const float* b1 = (const float*)d_in[3];
  const float* W2 = (const float*)d_in[4];
  const float* b2 = (const float*)d_in[5];
  float* out = (float*)d_out;

  const int N = in_sizes[0] / 128;
  const int E = in_sizes[1] / 2;
  const int* src = eidx;
  const int* dst = eidx + E;
  const int NBK = (N + BKT_NODES - 1) >> BKT_SHIFT;     // ~196 for N=100k
  const int CAP = (((E / NBK) * 3 / 2) + 255) & ~255;   // padded bucket cap

  auto align16 = [](size_t v) { return (v + 15) & ~(size_t)15; };
  char* w = (char*)d_ws;
  ushort* hb    = (ushort*)w; w += align16((size_t)N * 128 * 2);       // 25.6 MB
  ushort* h1b   = (ushort*)w; w += align16((size_t)N * 128 * 2);       // 25.6 MB
  int* csr_src  = (int*)w;    w += align16((size_t)NBK * CAP * 4);     // ~9.6 MB
  int2* rowinfo = (int2*)w;   w += align16((size_t)N * 8);             // 800 KB
  float* dinv   = (float*)w;  w += align16((size_t)N * 4);
  int* bcur     = (int*)w;    w += align16((size_t)(NBK + 1) * 4);
  // padded edge buffer aliases h1b (NBK*CAP*4 ~ 9.6 MB < 25.6 MB); consumed
  // by k_bktcsr before aggregate-1 writes h1b (stream-ordered).
  uint* ebuf = (uint*)h1b;

  hipMemsetAsync(bcur, 0, (size_t)NBK * 4, stream);
  const int SCB = (E + 256 * TPE - 1) / (256 * TPE);  // scatter blocks (~196)
  k_bktscatter<<<SCB, 256, 0, stream>>>(src, dst, bcur, ebuf, E, NBK, CAP);
  k_bktcsr<<<NBK, 256, 0, stream>>>(ebuf, bcur, CAP, rowinfo, dinv, csr_src, N);

  const int GB = (N + 127) / 128;
  const int AGG_BLOCKS = ((N + 3) / 4 + 3) / 4;  // 4 nodes/wave, 4 waves/block
  // layer 1: hb = bf16(dinv * (X @ W1)); h1b = bf16(relu(dinv*sum + b1))
  k_gemm_mfma<true><<<GB, 256, 0, stream>>>(x, W1, dinv, hb, N);
  k_aggregate<0><<<AGG_BLOCKS, 256, 0, stream>>>(
      hb, csr_src, rowinfo, dinv, b1, h1b, nullptr, N);
  // layer 2: hb = bf16(dinv * (h1b @ W2)); out = dinv*sum + b2 (fp32)
  k_gemm_mfma<false><<<GB, 256, 0, stream>>>(h1b, W2, dinv, hb, N);
  k_aggregate<1><<<AGG_BLOCKS, 256, 0, stream>>>(
      hb, csr_src, rowinfo, dinv, b2, nullptr, out, N);
}

// Round 13
// 214.195 us; speedup vs baseline: 1.1055x; 1.0405x over previous
//
#include <hip/hip_runtime.h>

// ---------------------------------------------------------------------------
// 2-layer GCN:  out = Ahat * (relu(Ahat * X * W1 + b1)) * W2 + b2
// Ahat = D^-1/2 (A + I) D^-1/2, deg computed with self-loops.
//
// Round-13: round-12 minus the non-temporal hints (they RAISED aggregate
// FETCH 189->196 MB and cost +4us/dispatch: nt csr_src loads discard lines
// shared across run boundaries; nt output stores don't help a capacity-bound
// h-table). Keeps the 6-kernel structure: padded csr_src, rowinfo(beg,deg),
// no cross-bucket scan.
//
// Aggregate roofline evidence (r6-r12): FETCH pinned at ~189 MB (computed
// compulsory per-XCD floor), fill ~2.9 TB/s; unroll x2, degree-sort, nt
// hints, and 2x occupancy all leave dur at 65-74us.
// ---------------------------------------------------------------------------

typedef __attribute__((ext_vector_type(8))) short bf16x8;
typedef __attribute__((ext_vector_type(4))) float f32x4;
typedef unsigned int uint;
typedef unsigned short ushort;

#define BKT_SHIFT 9
#define BKT_NODES 512   // nodes per bucket; NBK = ceil(N/512) <= 1024
#define TPE 32          // edges per thread in k_bktscatter

__device__ __forceinline__ ushort f2bf(float f) {  // RNE f32 -> bf16
  union { float f; uint u; } c; c.f = f;
  uint u = c.u;
  uint r = u + 0x7fffu + ((u >> 16) & 1u);
  return (ushort)(r >> 16);
}
__device__ __forceinline__ float bf_lo(uint u) {
  union { uint i; float f; } c; c.i = u << 16; return c.f;
}
__device__ __forceinline__ float bf_hi(uint u) {
  union { uint i; float f; } c; c.i = u & 0xffff0000u; return c.f;
}

// --------------------------- CSR build (single-pass, padded buckets) -------

// Scatter edges into padded bucket regions. Edges staged in registers
// (single global read); per-block LDS histogram -> one reservation atomic
// per (block,bucket) -> packed run writes. bcur holds RELATIVE counts
// (memset 0), absolute position = b*cap + rel.
__global__ __launch_bounds__(256) void k_bktscatter(const int* __restrict__ src,
                                                    const int* __restrict__ dst,
                                                    int* __restrict__ bcur,
                                                    uint* __restrict__ ebuf,
                                                    int E, int nbk, int cap) {
  __shared__ int h[1024];
  __shared__ int rbase[1024];
  int t = threadIdx.x;
  for (int i = t; i < nbk; i += 256) h[i] = 0;
  __syncthreads();
  int beg = blockIdx.x * (256 * TPE);
  int d[TPE], s[TPE];
#pragma unroll
  for (int j = 0; j < TPE; ++j) {
    int e = beg + j * 256 + t;
    bool v = e < E;
    d[j] = v ? dst[e] : -1;
    s[j] = v ? src[e] : 0;
    if (v) atomicAdd(&h[d[j] >> BKT_SHIFT], 1);
  }
  __syncthreads();
  for (int i = t; i < nbk; i += 256) {
    int c = h[i];
    rbase[i] = c ? atomicAdd(&bcur[i], c) : 0;  // relative base in bucket
    h[i] = 0;  // reuse as per-block cursor
  }
  __syncthreads();
#pragma unroll
  for (int j = 0; j < TPE; ++j) {
    if (d[j] >= 0) {
      int b = d[j] >> BKT_SHIFT;
      int rel = rbase[b] + atomicAdd(&h[b], 1);
      if (rel < cap)  // overflow guard (CAP ~ 1.5x mean, ~+45 sigma)
        ebuf[(size_t)b * cap + rel] =
            ((uint)s[j] << BKT_SHIFT) | (uint)(d[j] & (BKT_NODES - 1));
    }
  }
}

// One block per bucket (512 nodes): LDS node-histogram -> local scan ->
// rowinfo(beg,deg)/dinv -> csr_src scatter into the bucket's PADDED region.
// No cross-bucket scan needed: beg = b*cap + local exclusive offset.
__global__ __launch_bounds__(256) void k_bktcsr(const uint* __restrict__ ebuf,
                                                const int* __restrict__ bcur,
                                                int cap,
                                                int2* __restrict__ rowinfo,
                                                float* __restrict__ dinv,
                                                int* __restrict__ csr_src, int N) {
  __shared__ int ncnt[BKT_NODES];
  __shared__ int nscan[BKT_NODES];
  __shared__ int ncur[BKT_NODES];
  __shared__ int wtot[4];
  int t = threadIdx.x;
  int b = blockIdx.x;
  int node0 = b << BKT_SHIFT;
  int ebase = b * cap;
  int cnt = min(bcur[b], cap);
  const uint* ein = ebuf + (size_t)ebase;
  ncnt[t] = 0; ncnt[t + 256] = 0;
  ncur[t] = 0; ncur[t + 256] = 0;
  __syncthreads();
  for (int e = t; e < cnt; e += 256)
    atomicAdd(&ncnt[ein[e] & (BKT_NODES - 1)], 1);
  __syncthreads();
  // exclusive scan of 512 counts: 2 elems/thread + wave scan + wave offsets
  int v0 = ncnt[2 * t], v1 = ncnt[2 * t + 1];
  int s = v0 + v1;
  int lane = t & 63, wv = t >> 6;
  int inc = s;
#pragma unroll
  for (int off = 1; off < 64; off <<= 1) {
    int u = __shfl_up(inc, off);
    if (lane >= off) inc += u;
  }
  if (lane == 63) wtot[wv] = inc;
  __syncthreads();
  int woff = 0;
  for (int i = 0; i < wv; ++i) woff += wtot[i];
  int ex = woff + inc - s;
  nscan[2 * t] = ex;
  nscan[2 * t + 1] = ex + v0;
  int n0 = node0 + 2 * t;
  if (n0 < N) {
    rowinfo[n0] = make_int2(ebase + ex, v0);
    dinv[n0] = rsqrtf((float)v0 + 1.0f);
  }
  if (n0 + 1 < N) {
    rowinfo[n0 + 1] = make_int2(ebase + ex + v0, v1);
    dinv[n0 + 1] = rsqrtf((float)v1 + 1.0f);
  }
  __syncthreads();
  for (int e = t; e < cnt; e += 256) {
    uint u = ein[e];
    int l = u & (BKT_NODES - 1);
    int pos = ebase + nscan[l] + atomicAdd(&ncur[l], 1);
    csr_src[pos] = (int)(u >> BKT_SHIFT);
  }
}

// --------------------------- MFMA GEMM (dinv-scaled epilogue) --------------
// H'[n,128](bf16) = dinv[row] * (A[n,128] @ W[128,128]).
// A fp32 (layer1: X) or bf16 (layer2: h1). W staged in LDS chunk-major
// Bt[k/8][col][8]; frag layouts per m89.

__device__ __forceinline__ bf16x8 pack8(float4 u, float4 v) {
  bf16x8 r;
  r[0] = (short)f2bf(u.x); r[1] = (short)f2bf(u.y);
  r[2] = (short)f2bf(u.z); r[3] = (short)f2bf(u.w);
  r[4] = (short)f2bf(v.x); r[5] = (short)f2bf(v.y);
  r[6] = (short)f2bf(v.z); r[7] = (short)f2bf(v.w);
  return r;
}

template <bool A_IS_F32>
__global__ __launch_bounds__(256) void k_gemm_mfma(const void* __restrict__ A,
                                                   const float* __restrict__ Wf,
                                                   const float* __restrict__ dinv,
                                                   ushort* __restrict__ H, int n) {
  __shared__ __align__(16) ushort Bt[16 * 128 * 8];  // [chunk][col][8]
  int t = threadIdx.x;
  for (int id = t; id < 16 * 128; id += 256) {
    int col = id & 127, ch = id >> 7;
    ushort us[8];
#pragma unroll
    for (int j = 0; j < 8; ++j) us[j] = f2bf(Wf[(ch * 8 + j) * 128 + col]);
    uint4 p;
    p.x = (uint)us[0] | ((uint)us[1] << 16);
    p.y = (uint)us[2] | ((uint)us[3] << 16);
    p.z = (uint)us[4] | ((uint)us[5] << 16);
    p.w = (uint)us[6] | ((uint)us[7] << 16);
    *(uint4*)&Bt[id * 8] = p;
  }
  __syncthreads();

  int wv = t >> 6, lane = t & 63;
  int r16 = lane & 15, kg = lane >> 4;
  int row0 = blockIdx.x * 128 + wv * 32;
  f32x4 acc[2][8] = {};

#pragma unroll
  for (int ks = 0; ks < 4; ++ks) {
    bf16x8 a0, a1;
    if (A_IS_F32) {
      const float* Af = (const float*)A;
      int r = min(row0 + r16, n - 1);
      const float* p = &Af[(size_t)r * 128 + ks * 32 + kg * 8];
      a0 = pack8(*(const float4*)p, *(const float4*)(p + 4));
      r = min(row0 + 16 + r16, n - 1);
      p = &Af[(size_t)r * 128 + ks * 32 + kg * 8];
      a1 = pack8(*(const float4*)p, *(const float4*)(p + 4));
    } else {
      const ushort* Ab = (const ushort*)A;
      int r = min(row0 + r16, n - 1);
      a0 = *(const bf16x8*)&Ab[(size_t)r * 128 + ks * 32 + kg * 8];
      r = min(row0 + 16 + r16, n - 1);
      a1 = *(const bf16x8*)&Ab[(size_t)r * 128 + ks * 32 + kg * 8];
    }
#pragma unroll
    for (int tc = 0; tc < 8; ++tc) {
      bf16x8 b = *(const bf16x8*)&Bt[(((ks * 4 + kg) * 128) + tc * 16 + r16) * 8];
      acc[0][tc] = __builtin_amdgcn_mfma_f32_16x16x32_bf16(a0, b, acc[0][tc], 0, 0, 0);
      acc[1][tc] = __builtin_amdgcn_mfma_f32_16x16x32_bf16(a1, b, acc[1][tc], 0, 0, 0);
    }
  }

#pragma unroll
  for (int rt = 0; rt < 2; ++rt)
#pragma unroll
    for (int rg = 0; rg < 4; ++rg) {
      int row = row0 + rt * 16 + kg * 4 + rg;
      if (row < n) {
        float dv = dinv[row];
#pragma unroll
        for (int tc = 0; tc < 8; ++tc)
          H[(size_t)row * 128 + tc * 16 + r16] = f2bf(dv * acc[rt][tc][rg]);
      }
    }
}

// --------------------------- Aggregation -----------------------------------
// 4 nodes/wave (sequential ids). sub=lane>>4 owns node, lane&15 covers 16B
// (8 bf16 cols) of the 256B row. H pre-scaled by dinv[src]: inner loop =
// gather + 8 adds per edge. out_i = dinv_i * (h'_i + sum h'_src) + bias.
// 8-edge unroll for MLP. MODE 0: bf16 + relu (L1). MODE 1: fp32 (L2).

__device__ __forceinline__ void add8(uint4 u, float* a) {
  a[0] += bf_lo(u.x); a[1] += bf_hi(u.x);
  a[2] += bf_lo(u.y); a[3] += bf_hi(u.y);
  a[4] += bf_lo(u.z); a[5] += bf_hi(u.z);
  a[6] += bf_lo(u.w); a[7] += bf_hi(u.w);
}

template <int MODE>
__global__ __launch_bounds__(256) void k_aggregate(
    const ushort* __restrict__ H, const int* __restrict__ csr_src,
    const int2* __restrict__ rowinfo, const float* __restrict__ dinv,
    const float* __restrict__ bias, ushort* __restrict__ outb,
    float* __restrict__ outf, int n) {
  int wave = (blockIdx.x * blockDim.x + threadIdx.x) >> 6;
  int lane = threadIdx.x & 63;
  int sub = lane >> 4, c16 = lane & 15;
  int node = wave * 4 + sub;
  bool valid = node < n;
  int nd = valid ? node : (n - 1);

  float di = dinv[nd];
  int2 ri = rowinfo[nd];
  int beg = ri.x;
  int end = beg + (valid ? ri.y : 0);

  float acc[8] = {};
  uint4 sv = *(const uint4*)&H[(size_t)nd * 128 + c16 * 8];  // self (pre-scaled)
  add8(sv, acc);

  int e = beg;
  for (; e + 7 < end; e += 8) {
    int s[8];
    uint4 u[8];
#pragma unroll
    for (int j = 0; j < 8; ++j) s[j] = csr_src[e + j];
#pragma unroll
    for (int j = 0; j < 8; ++j)
      u[j] = *(const uint4*)&H[(size_t)s[j] * 128 + c16 * 8];
#pragma unroll
    for (int j = 0; j < 8; ++j) add8(u[j], acc);
  }
  for (; e + 3 < end; e += 4) {
    int s0 = csr_src[e], s1 = csr_src[e + 1];
    int s2 = csr_src[e + 2], s3 = csr_src[e + 3];
    uint4 u0 = *(const uint4*)&H[(size_t)s0 * 128 + c16 * 8];
    uint4 u1 = *(const uint4*)&H[(size_t)s1 * 128 + c16 * 8];
    uint4 u2 = *(const uint4*)&H[(size_t)s2 * 128 + c16 * 8];
    uint4 u3 = *(const uint4*)&H[(size_t)s3 * 128 + c16 * 8];
    add8(u0, acc); add8(u1, acc); add8(u2, acc); add8(u3, acc);
  }
  for (; e < end; ++e) {
    int s0 = csr_src[e];
    uint4 u0 = *(const uint4*)&H[(size_t)s0 * 128 + c16 * 8];
    add8(u0, acc);
  }

  float4 bA = *(const float4*)&bias[c16 * 8];
  float4 bB = *(const float4*)&bias[c16 * 8 + 4];
  float o[8];
  o[0] = fmaf(di, acc[0], bA.x); o[1] = fmaf(di, acc[1], bA.y);
  o[2] = fmaf(di, acc[2], bA.z); o[3] = fmaf(di, acc[3], bA.w);
  o[4] = fmaf(di, acc[4], bB.x); o[5] = fmaf(di, acc[5], bB.y);
  o[6] = fmaf(di, acc[6], bB.z); o[7] = fmaf(di, acc[7], bB.w);

  if (!valid) return;
  if (MODE == 0) {
#pragma unroll
    for (int i = 0; i < 8; ++i) o[i] = fmaxf(o[i], 0.f);
    uint4 w;
    w.x = (uint)f2bf(o[0]) | ((uint)f2bf(o[1]) << 16);
    w.y = (uint)f2bf(o[2]) | ((uint)f2bf(o[3]) << 16);
    w.z = (uint)f2bf(o[4]) | ((uint)f2bf(o[5]) << 16);
    w.w = (uint)f2bf(o[6]) | ((uint)f2bf(o[7]) << 16);
    *(uint4*)&outb[(size_t)node * 128 + c16 * 8] = w;
  } else {
    *(float4*)&outf[(size_t)node * 128 + c16 * 8] =
        make_float4(o[0], o[1], o[2], o[3]);
    *(float4*)&outf[(size_t)node * 128 + c16 * 8 + 4] =
        make_float4(o[4], o[5], o[6], o[7]);
  }
}

// ---------------------------------------------------------------------------

extern "C" void kernel_launch(void* const* d_in, const int* in_sizes, int n_in,
                              void* d_out, int out_size, void* d_ws, size_t ws_size,
                              hipStream_t stream) {
  const float* x  = (const float*)d_in[0];
  const int* eidx = (const int*)d_in[1];
  const float* W1 = (const float*)d_in[2];
  const float* b1 = (const float*)d_in[3];
  const float* W2 = (const float*)d_in[4];
  const float* b2 = (const float*)d_in[5];
  float* out = (float*)d_out;

  const int N = in_sizes[0] / 128;
  const int E = in_sizes[1] / 2;
  const int* src = eidx;
  const int* dst = eidx + E;
  const int NBK = (N + BKT_NODES - 1) >> BKT_SHIFT;     // ~196 for N=100k
  const int CAP = (((E / NBK) * 3 / 2) + 255) & ~255;   // padded bucket cap

  auto align16 = [](size_t v) { return (v + 15) & ~(size_t)15; };
  char* w = (char*)d_ws;
  ushort* hb    = (ushort*)w; w += align16((size_t)N * 128 * 2);       // 25.6 MB
  ushort* h1b   = (ushort*)w; w += align16((size_t)N * 128 * 2);       // 25.6 MB
  int* csr_src  = (int*)w;    w += align16((size_t)NBK * CAP * 4);     // ~9.6 MB
  int2* rowinfo = (int2*)w;   w += align16((size_t)N * 8);             // 800 KB
  float* dinv   = (float*)w;  w += align16((size_t)N * 4);
  int* bcur     = (int*)w;    w += align16((size_t)(NBK + 1) * 4);
  // padded edge buffer aliases h1b (NBK*CAP*4 ~ 9.6 MB < 25.6 MB); consumed
  // by k_bktcsr before aggregate-1 writes h1b (stream-ordered).
  uint* ebuf = (uint*)h1b;

  hipMemsetAsync(bcur, 0, (size_t)NBK * 4, stream);
  const int SCB = (E + 256 * TPE - 1) / (256 * TPE);  // scatter blocks (~196)
  k_bktscatter<<<SCB, 256, 0, stream>>>(src, dst, bcur, ebuf, E, NBK, CAP);
  k_bktcsr<<<NBK, 256, 0, stream>>>(ebuf, bcur, CAP, rowinfo, dinv, csr_src, N);

  const int GB = (N + 127) / 128;
  const int AGG_BLOCKS = ((N + 3) / 4 + 3) / 4;  // 4 nodes/wave, 4 waves/block
  // layer 1: hb = bf16(dinv * (X @ W1)); h1b = bf16(relu(dinv*sum + b1))
  k_gemm_mfma<true><<<GB, 256, 0, stream>>>(x, W1, dinv, hb, N);
  k_aggregate<0><<<AGG_BLOCKS, 256, 0, stream>>>(
      hb, csr_src, rowinfo, dinv, b1, h1b, nullptr, N);
  // layer 2: hb = bf16(dinv * (h1b @ W2)); out = dinv*sum + b2 (fp32)
  k_gemm_mfma<false><<<GB, 256, 0, stream>>>(h1b, W2, dinv, hb, N);
  k_aggregate<1><<<AGG_BLOCKS, 256, 0, stream>>>(
      hb, csr_src, rowinfo, dinv, b2, nullptr, out, N);
}